// Round 17
// baseline (47.943 us; speedup 1.0000x reference)
//
#include <hip/hip_runtime.h>
#include <hip/hip_bf16.h>

// Map physical block -> (batch, chunk) with XCD affinity: XCD k serves
// batches {k, k+8}. (R12 champion mapping.)
__device__ __forceinline__ void map_block(int j, int B, int bpb,
                                          int& batch, int& chunk) {
    if ((B & 7) == 0) {
        int xcd = j & 7;
        int g = j >> 3;
        int per = B >> 3;
        batch = xcd + 8 * (g % per);
        chunk = g / per;
    } else {
        batch = j / bpb;
        chunk = j - batch * bpb;
    }
}

// Fill the BEV output with EMPTY (255.0f), regular float4 stores (L2-absorbed;
// nt variant measured 4us slower overall in R16). R12 form.
__global__ void bev_fill_kernel(float4* __restrict__ out,
                                const int* __restrict__ p_bev_h,
                                const int* __restrict__ p_bev_w,
                                int out_size) {
    const int img  = (*p_bev_h) * (*p_bev_w);
    const int img4 = img >> 2;
    const int B    = out_size / img;
    const int bpb  = (img4 + 1023) >> 10;

    int batch, chunk;
    map_block(blockIdx.x, B, bpb, batch, chunk);
    if (batch >= B) return;

    float4* dst = out + (size_t)batch * (size_t)img4;
    int base = (chunk << 10) + threadIdx.x;
    const float4 v = make_float4(255.0f, 255.0f, 255.0f, 255.0f);
#pragma unroll
    for (int k = 0; k < 4; ++k) {
        int idx = base + (k << 8);
        if (idx < img4) dst[idx] = v;
    }
}

// Scatter labels into BEV, TEMPORALLY PHASED by z-half: launched twice,
// phase 0 stores only rows z < bev_h/2, phase 1 the rest. Each launch's
// device-wide store footprint is 33.5MB -> ~4.2MB per XCD L2 (vs 8.4MB
// unphased), so RMW line-fetches stay L2-resident. Inputs re-read per phase
// (L3-warm). Index math = class E (verified R11): single f32 rounding of the
// EXACT quotient a/(0.1*scale) == f32((f64)a * rd), rd = f64 1/(0.1*scale)
// (== 10.0 exactly for scale=1), asm-opaqued so no pass narrows the f64
// chain to an f32 multiply. Then f32 add 512.0f, rintf (RNE), trunc-to-int,
// drop OOB, racy last-writer-wins.
__global__ void bev_scatter_kernel(const float* __restrict__ labels,
                                   const float* __restrict__ pc,
                                   const int* __restrict__ p_bev_h,
                                   const int* __restrict__ p_bev_w,
                                   const int* __restrict__ p_scale,
                                   float* __restrict__ out,
                                   int n_pts, int out_size, int phase) {
    const int bev_h = *p_bev_h;
    const int bev_w = *p_bev_w;
    const int scale = *p_scale;
    const double res_d = 0.1 * (double)scale;
    const float half_w = (float)(bev_w / 2);
    const int half_h = bev_h >> 1;

    double rd = 1.0 / res_d;
    asm volatile("" : "+v"(rd));

    const int img = bev_h * bev_w;
    const int B = out_size / img;
    const int HW = n_pts / B;
    const int bpb = (HW + 1023) >> 10;          // 1024 points per block

    int batch, chunk;
    map_block(blockIdx.x, B, bpb, batch, chunk);
    if (batch >= B) return;

    int r = ((chunk << 8) + threadIdx.x) << 2;
    if (r >= HW) return;

    const float* pcb = pc + (size_t)batch * 3u * (size_t)HW;
    float4 lab = *(const float4*)(labels + (size_t)batch * (size_t)HW + r);
    float4 x0  = *(const float4*)(pcb + r);
    float4 z0  = *(const float4*)(pcb + 2 * (size_t)HW + r);

    float* outb = out + (size_t)batch * (size_t)img;

    float xs[4] = {x0.x, x0.y, x0.z, x0.w};
    float zs[4] = {z0.x, z0.y, z0.z, z0.w};
    float ls[4] = {lab.x, lab.y, lab.z, lab.w};

#pragma unroll
    for (int k = 0; k < 4; ++k) {
        float xq = (float)((double)(-xs[k]) * rd);   // class-E quotient
        float zq = (float)((double)zs[k] * rd);
        float xf = rintf(__fadd_rn(xq, half_w));
        float zf = rintf(zq);
        int xi = (int)xf;
        int zi = (int)zf;
        if (xi >= 0 && xi < bev_w && zi >= 0 && zi < bev_h) {
            int ph = (zi >= half_h) ? 1 : 0;
            if (ph == phase)
                outb[(size_t)zi * (size_t)bev_w + (size_t)xi] = ls[k];
        }
    }
}

extern "C" void kernel_launch(void* const* d_in, const int* in_sizes, int n_in,
                              void* d_out, int out_size, void* d_ws, size_t ws_size,
                              hipStream_t stream) {
    const float* labels = (const float*)d_in[0];   // (B,1,H,W) f32
    const float* pc     = (const float*)d_in[1];   // (B,3,H,W) f32
    const int* p_bev_h  = (const int*)d_in[2];
    const int* p_bev_w  = (const int*)d_in[3];
    const int* p_scale  = (const int*)d_in[4];
    float* out = (float*)d_out;

    int n_pts = in_sizes[0];

    // 1) fill with EMPTY (regular stores, R12 form)
    int fill_blocks = (out_size + 4095) / 4096;
    bev_fill_kernel<<<fill_blocks, 256, 0, stream>>>((float4*)out, p_bev_h,
                                                     p_bev_w, out_size);

    // 2) scatter, temporally phased by z-half (L2-resident store footprint)
    int sc_blocks = (n_pts + 1023) / 1024;
    bev_scatter_kernel<<<sc_blocks, 256, 0, stream>>>(labels, pc, p_bev_h,
                                                      p_bev_w, p_scale, out,
                                                      n_pts, out_size, 0);
    bev_scatter_kernel<<<sc_blocks, 256, 0, stream>>>(labels, pc, p_bev_h,
                                                      p_bev_w, p_scale, out,
                                                      n_pts, out_size, 1);
}